// Round 1
// 611.801 us; speedup vs baseline: 1.4894x; 1.4894x over previous
//
#include <hip/hip_runtime.h>
#include <hip/hip_bf16.h>
#include <cstdint>

typedef float floatx4 __attribute__((ext_vector_type(4)));
typedef short short4v __attribute__((ext_vector_type(4)));
typedef unsigned int uint2v __attribute__((ext_vector_type(2)));

#define HH 128
#define WW 128
#define NCH 256
#define IMG 16384        // HH*WW
#define SBUF 24576       // one K=16 src buffer: 384 px * 16 ch * 4 B

// fp32 -> bf16 (RNE via hardware cvt; compiler fuses pairs to v_cvt_pk_bf16_f32)
__device__ __forceinline__ short bf16s(float x) {
  return __builtin_bit_cast(short, (__bf16)x);
}

__device__ __forceinline__ short4v cvtA(const float* a) {
  short4v r;
  r.x = bf16s(a[0]); r.y = bf16s(a[1]); r.z = bf16s(a[2]); r.w = bf16s(a[3]);
  return r;
}

// convert 4 staged fp32 channels to a bf16 B-fragment, zeroing OOB pixels
__device__ __forceinline__ short4v cvtB(floatx4 f, unsigned mwv) {
  short4v r;
  r.x = bf16s(f.x); r.y = bf16s(f.y); r.z = bf16s(f.z); r.w = bf16s(f.w);
  uint2v u = __builtin_bit_cast(uint2v, r);
  u.x &= mwv; u.y &= mwv;
  return __builtin_bit_cast(short4v, u);
}

__device__ __forceinline__ floatx4 mfma16(short4v a, short4v b, floatx4 c) {
#if __has_builtin(__builtin_amdgcn_mfma_f32_16x16x16bf16_1k)
  return __builtin_amdgcn_mfma_f32_16x16x16bf16_1k(a, b, c, 0, 0, 0);
#else
  asm("v_mfma_f32_16x16x16_bf16 %0, %1, %2, %0" : "+v"(c) : "v"(a), "v"(b));
  return c;
#endif
}

// Stage 384 px x 16 ch of fp32 src into LDS via direct global->LDS DMA.
// Chunk = one instruction = 64 lanes * 4 B = 16 px x 4 ch, LDS-contiguous:
// layout [pxblk P][chq Q][px&15][ch&3], chunk (P,Q) at (P*4+Q)*256 bytes.
// Lane l within a chunk: px = 16P + (l>>2), ch = 4Q + (l&3)  ->  lds + l*4.
__device__ __forceinline__ void stage16(const float* srcp, const int* spoff,
                                        int wv, char* dst) {
  #pragma unroll
  for (int cc = 0; cc < 24; ++cc) {
    const int Q = cc & 3, i = cc >> 2;
    const float* gp = srcp + spoff[i] + Q * 4 * IMG;
    char* lp = dst + ((wv * 24 + cc) << 8);
    __builtin_amdgcn_global_load_lds(
        (const __attribute__((address_space(1))) void*)(uintptr_t)gp,
        (__attribute__((address_space(3))) void*)(uintptr_t)lp, 4, 0, 0);
  }
}

// Target A-fragments straight to registers: 4 ch (k = 4*kq + j) for the
// lane's two M-tile pixels (rows br+0/1 and br+2/3 of the wave block).
__device__ __forceinline__ void tload8(const float* tg, float* araw) {
  #pragma unroll
  for (int j = 0; j < 4; ++j) {
    araw[j]     = tg[(size_t)j * IMG];
    araw[4 + j] = tg[(size_t)j * IMG + 2 * WW];
  }
}

__global__ __launch_bounds__(256, 2) void lfc_kernel(
    const float* __restrict__ fsrc,
    const float* __restrict__ ftgt,
    float* __restrict__ out)
{
  __shared__ char smem[49152];  // 2 x 24 KB staging; 48 KB extraction (aliased)

  const int tid  = threadIdx.x;
  const int lane = tid & 63;
  const int wv   = tid >> 6;

  // XCD-aware bijective swizzle: 8 XCDs get contiguous chunks of the grid so
  // halo-sharing neighbor blocks hit the same per-XCD L2.
  const int id    = blockIdx.x + (blockIdx.y << 3) + (blockIdx.z << 7);
  const int chunk = (int)(gridDim.z << 4);            // (128*B)/8
  const int nid   = (id & 7) * chunk + (id >> 3);
  const int b     = nid >> 7;
  const int R0    = ((nid >> 3) & 15) << 3;           // 8-row region
  const int C0    = (nid & 7) << 4;                   // 16-col region

  const int br = (wv >> 1) << 2;   // wave block origin in region: 0 or 4
  const int bc = (wv & 1) << 3;    // 0 or 8

  const size_t bbase = (size_t)b * NCH * IMG;

  const int n  = lane & 15;   // A: m within M-tile / B: n within N-tile
  const int kq = lane >> 4;   // k-quad (k = 4*kq + j)

  // ---- A (target) register-fragment addressing ----
  const int gh = R0 + br + (n >> 3);
  const int gw = C0 + bc + (n & 7);
  const float* tgap = ftgt + bbase + (size_t)(kq * 4) * IMG
      + (size_t)(gh * WW + gw);

  // ---- src staging per-lane global offsets (clamped; OOB masked at read) ----
  int spoff[6];
  #pragma unroll
  for (int i = 0; i < 6; ++i) {
    const int p = ((wv * 6 + i) << 4) + (lane >> 2);   // tile-flat px 0..383
    int gr = R0 - 4 + p / 24;
    int gc = C0 - 4 + p % 24;
    gr = min(max(gr, 0), HH - 1);
    gc = min(max(gc, 0), WW - 1);
    spoff[i] = gr * WW + gc + (lane & 3) * IMG;
  }

  // ---- B fragment LDS offsets + zero-pad masks (constant across K) ----
  int boffs[12];
  unsigned mw[12];
  const unsigned colmask =
      ((unsigned)(C0 - 4 + bc + n) < (unsigned)WW) ? 0xFFFFFFFFu : 0u;
  #pragma unroll
  for (int t = 0; t < 12; ++t) {
    const int p = (br + t) * 24 + bc + n;
    boffs[t] = ((p >> 4) << 10) + (kq << 8) + ((p & 15) << 4);
    mw[t] = ((unsigned)(R0 - 4 + br + t) < (unsigned)HH) ? colmask : 0u;
  }

  floatx4 acc0[12], acc1[12];
  const floatx4 zero4 = {0.f, 0.f, 0.f, 0.f};
  #pragma unroll
  for (int t = 0; t < 12; ++t) { acc0[t] = zero4; acc1[t] = zero4; }

  const float* srcp = fsrc + bbase;

  // prologue: stage K-half 0, prefetch target frag 0
  stage16(srcp, spoff, wv, smem);
  float araw[8];
  tload8(tgap, araw);
  __syncthreads();   // compiler drains vmcnt before the barrier -> buf0 ready

  // 16 K-halves of 16 ch; double-buffered; ONE barrier per step.
  // stage(h+1) is issued at the top so its latency hides under the whole
  // step body; the end-of-step barrier (with its vmcnt drain) publishes it.
  #pragma unroll 2
  for (int h = 0; h < 16; ++h) {
    const int cur = (h & 1) ? SBUF : 0;
    if (h < 15) {
      srcp += (size_t)16 * IMG;
      stage16(srcp, spoff, wv, smem + (SBUF - cur));
    }
    const short4v a0 = cvtA(araw);
    const short4v a1 = cvtA(araw + 4);
    if (h < 15) {
      tgap += (size_t)16 * IMG;
      tload8(tgap, araw);           // register prefetch for step h+1
    }
    const char* rb = smem + cur;
    #pragma unroll
    for (int t = 0; t < 12; ++t) {
      const floatx4 f = *(const floatx4*)(rb + boffs[t]);
      const short4v bb = cvtB(f, mw[t]);
      acc0[t] = mfma16(a0, bb, acc0[t]);
      acc1[t] = mfma16(a1, bb, acc1[t]);
    }
    __syncthreads();
  }

  // ---------------- extraction / relu / L2-normalize / store ----------------
  float* ew = (float*)smem + wv * 3072;  // 12 KB per wave: [t(12)][uc(16)][m(16)]
  const int mm = lane >> 2;   // pixel handled by this lane in read phase
  const int dq = lane & 3;    // displacement subgroup

  #pragma unroll
  for (int mt = 0; mt < 2; ++mt) {
    // dump this M-tile's Gram: D col(uc) = lane&15, row(m) = (lane>>4)*4+i
    #pragma unroll
    for (int t = 0; t < 12; ++t) {
      floatx4 v = (mt == 0) ? acc0[t] : acc1[t];
      *(floatx4*)((char*)ew + (t << 10) + ((lane & 15) << 6) + ((lane >> 4) << 4)) = v;
    }
    __syncthreads();
    const int px = (mt << 4) | mm;   // wave-block px 0..31
    const int r  = px >> 3;          // block row 0..3
    const int c  = px & 7;           // block col 0..7
    float vals[21];
    float ss = 0.f;
    #pragma unroll
    for (int j = 0; j < 21; ++j) {
      const int d = dq + (j << 2);
      float v = 0.f;
      if (d < 81) {
        const int dh = d / 9, dw = d % 9;
        v = ew[(r + dh) * 256 + (c + dw) * 16 + mm];
        v = fmaxf(v, 0.f);
      }
      vals[j] = v;
      ss += v * v;
    }
    ss += __shfl_xor(ss, 1);
    ss += __shfl_xor(ss, 2);
    const float inv = 1.0f / fmaxf(sqrtf(ss), 1e-12f);
    const int ogh = R0 + br + r;
    const int ogw = C0 + bc + c;
    float* op = out + (size_t)b * 81 * IMG + (size_t)ogh * WW + ogw;
    #pragma unroll
    for (int j = 0; j < 21; ++j) {
      const int d = dq + (j << 2);
      if (d < 81) op[(size_t)d * IMG] = vals[j] * inv;
    }
    __syncthreads();  // protect ew before next M-tile overwrites it
  }
}

extern "C" void kernel_launch(void* const* d_in, const int* in_sizes, int n_in,
                              void* d_out, int out_size, void* d_ws, size_t ws_size,
                              hipStream_t stream) {
  const float* fsrc = (const float*)d_in[0];  // feature_source
  const float* ftgt = (const float*)d_in[1];  // feature_target
  float* out = (float*)d_out;
  const int B = in_sizes[0] / (NCH * IMG);
  dim3 grid(WW / 16, HH / 8, B);
  lfc_kernel<<<grid, 256, 0, stream>>>(fsrc, ftgt, out);
}